// Round 3
// baseline (441.750 us; speedup 1.0000x reference)
//
#include <hip/hip_runtime.h>
#include <stdint.h>

typedef unsigned short u16;
typedef unsigned int u32;
typedef __bf16 bf16x8 __attribute__((ext_vector_type(8)));
typedef float f32x4 __attribute__((ext_vector_type(4)));
typedef float f32x16 __attribute__((ext_vector_type(16)));

#define SEQ 2048
#define BZ 16
#define DIM 1024

__device__ __forceinline__ u16 f2bf(float f) {
    union { float f; u32 u; } a; a.f = f;
    u32 r = a.u + 0x7FFFu + ((a.u >> 16) & 1u);   // RNE
    return (u16)(r >> 16);
}
__device__ __forceinline__ float bf2f(u16 u) {
    union { u32 u; float f; } a; a.u = ((u32)u) << 16;
    return a.f;
}
__device__ __forceinline__ void async16(const u16* g, u16* l) {
    __builtin_amdgcn_global_load_lds(
        (const __attribute__((address_space(1))) void*)g,
        (__attribute__((address_space(3))) void*)l, 16, 0, 0);
}

// ---------------------------------------------------------------------------
// K0a: xb[b][s][d] = bf16(x[s][b][d])   (transpose s<->b, convert)
// ---------------------------------------------------------------------------
__global__ void convert_x(const float* __restrict__ x, u16* __restrict__ xb)
{
    int s = blockIdx.x;
    int t = threadIdx.x;
    const float4* src = (const float4*)(x + (size_t)s * BZ * DIM);
    #pragma unroll
    for (int j = 0; j < 16; j++) {
        int idx = j * 256 + t;              // float4 index in [0, 4096)
        float4 v = src[idx];
        int e = idx * 4;
        int b = e >> 10, d = e & 1023;
        u32 lo = f2bf(v.x) | ((u32)f2bf(v.y) << 16);
        u32 hi = f2bf(v.z) | ((u32)f2bf(v.w) << 16);
        *(uint2*)(xb + ((size_t)b * SEQ + s) * DIM + d) = make_uint2(lo, hi);
    }
}

// ---------------------------------------------------------------------------
// K0: transpose+convert.  z<16: Wbt[z][f][e] = W[id_z][e][f]   (bf16)
//     z==16:              Wt[d][e]   = W_base[e][d]            (bf16)
// ---------------------------------------------------------------------------
__global__ void transpose_cvt(const float* __restrict__ W,
                              const float* __restrict__ W_base,
                              const int* __restrict__ lang_ids,
                              const int* __restrict__ dict_len,
                              u16* __restrict__ Wt,
                              u16* __restrict__ Wbt)
{
    int z = blockIdx.z;
    const float* S;
    u16* D;
    if (z < BZ) {
        int id = dict_len[0] - 1 - lang_ids[z];
        S = W + (size_t)id * DIM * DIM;
        D = Wbt + (size_t)z * DIM * DIM;
    } else {
        S = W_base;
        D = Wt;
    }
    __shared__ float tile[32][33];
    int tx = threadIdx.x, ty = threadIdx.y;       // 32 x 8
    int x0 = blockIdx.x * 32, y0 = blockIdx.y * 32;
    #pragma unroll
    for (int i = 0; i < 4; i++)
        tile[ty + 8 * i][tx] = S[(size_t)(y0 + ty + 8 * i) * DIM + x0 + tx];
    __syncthreads();
    #pragma unroll
    for (int i = 0; i < 4; i++)
        D[(size_t)(x0 + ty + 8 * i) * DIM + y0 + tx] = f2bf(tile[tx][ty + 8 * i]);
}

// ---------------------------------------------------------------------------
// K1: bb[b][f] = sum_e b_base[e] * Wbt[b][f][e]  + bias[id_b][f]
// ---------------------------------------------------------------------------
__global__ void bb_kernel(const u16* __restrict__ Wbt,
                          const float* __restrict__ b_base,
                          const float* __restrict__ bias,
                          const int* __restrict__ lang_ids,
                          const int* __restrict__ dict_len,
                          float* __restrict__ bb)
{
    int gw = blockIdx.x * 4 + (threadIdx.x >> 6);
    int b = gw >> 10;
    int f = gw & 1023;
    int lane = threadIdx.x & 63;
    const u16* row = Wbt + ((size_t)b * DIM + f) * DIM;
    float s = 0.f;
    #pragma unroll
    for (int i = 0; i < DIM / 64; i++)
        s += bf2f(row[lane + 64 * i]) * b_base[lane + 64 * i];
    #pragma unroll
    for (int off = 32; off; off >>= 1)
        s += __shfl_xor(s, off, 64);
    if (lane == 0) {
        int id = dict_len[0] - 1 - lang_ids[b];
        bb[b * DIM + f] = s + bias[(size_t)id * DIM + f];
    }
}

// ---------------------------------------------------------------------------
// Shared GEMM geometry: block tile 128(M) x 256(N), BK=32, 4 waves (1Mx4N),
// wave tile 128x64 as 4x2 frags of mfma_f32_32x32x16_bf16.
// LDS: A [128][32] u16, B [256][32] u16, double-buffered = 48 KiB.
// Swizzle: LDS[row][slot] (slot = 8-u16 chunk) holds global chunk
// slot^(row&3); staging pre-swizzles the per-lane GLOBAL address (LDS dest
// linear, required by global_load_lds); ds_read applies the same XOR.
// Conflict-free by enumeration: slot-group mod 8 covers all 8 with 8 lanes
// each (the b128 floor) for both kk phases.
// ---------------------------------------------------------------------------

// A-frag (m,kk) read offset for lane l (u16 units, rel. to A buffer base)
#define RD_A(m, kk, l) (((m)*32 + ((l) & 31)) * 32 + ((((kk)*2 + ((l) >> 5)) ^ ((l) & 3)) * 8))
// B-frag (wave w, n, kk)
#define RD_B(w, n, kk, l) (((w)*64 + (n)*32 + ((l) & 31)) * 32 + ((((kk)*2 + ((l) >> 5)) ^ ((l) & 3)) * 8))

// ---------------------------------------------------------------------------
// K2: CT[b][f][d] = sum_e Wbt[b][f][e] * Wt[d][e]   (bf16 out)
// grid = 512 blocks (8 Mtile x 4 Ntile x 16 batch), XCD-swizzled
// ---------------------------------------------------------------------------
__global__ __launch_bounds__(256, 2)
void gemm1_kernel(const u16* __restrict__ Wbt,
                  const u16* __restrict__ Wt,
                  u16* __restrict__ CT)
{
    int bid = blockIdx.x;
    int virt = ((bid & 7) << 6) + (bid >> 3);     // bijective, 512 % 8 == 0
    int b    = virt >> 5;                         // 32 blocks per batch
    int rem  = virt & 31;
    int m0   = (rem >> 2) << 7;                   // f-tile base (128)
    int n0   = (rem & 3) << 8;                    // d-tile base (256)

    const u16* A = Wbt + (size_t)b * DIM * DIM;   // [f][e]
    const u16* B = Wt;                            // [d][e]
    u16* C = CT + (size_t)b * DIM * DIM;          // [f][d]

    __shared__ u16 As[2 * 128 * 32];
    __shared__ u16 Bs[2 * 256 * 32];

    int tid = threadIdx.x;
    int w = tid >> 6, l = tid & 63;
    int lr = l & 31, h = l >> 5;

    // staging: per thread 2 A-loads + 4 B-loads of 16B, pre-swizzled source
    int srow = l >> 2;                            // row within 16-row group
    int chunk = (l & 3) ^ (srow & 3);             // global chunk for this slot
    const u16* gA[2]; const u16* gB[4];
    int lA[2], lB[4];
    #pragma unroll
    for (int j = 0; j < 2; j++) {
        int row = w * 32 + j * 16 + srow;
        gA[j] = A + (size_t)(m0 + row) * DIM + chunk * 8;
        lA[j] = (w * 32 + j * 16) * 32;           // wave-uniform LDS base
    }
    #pragma unroll
    for (int j = 0; j < 4; j++) {
        int row = w * 64 + j * 16 + srow;
        gB[j] = B + (size_t)(n0 + row) * DIM + chunk * 8;
        lB[j] = (w * 64 + j * 16) * 32;
    }

    f32x16 acc[4][2];
    #pragma unroll
    for (int m = 0; m < 4; m++)
        #pragma unroll
        for (int n = 0; n < 2; n++)
            #pragma unroll
            for (int e = 0; e < 16; e++) acc[m][n][e] = 0.f;

    // prologue: stage K-tile 0 into buffer 0
    #pragma unroll
    for (int j = 0; j < 2; j++) async16(gA[j], As + lA[j]);
    #pragma unroll
    for (int j = 0; j < 4; j++) async16(gB[j], Bs + lB[j]);
    #pragma unroll
    for (int j = 0; j < 2; j++) gA[j] += 32;
    #pragma unroll
    for (int j = 0; j < 4; j++) gB[j] += 32;
    __syncthreads();

    int cur = 0;
    for (int t = 0; t < DIM / 32; t++) {
        if (t + 1 < DIM / 32) {                   // stage next tile -> other buf
            int ao = (cur ^ 1) * 4096, bo = (cur ^ 1) * 8192;
            #pragma unroll
            for (int j = 0; j < 2; j++) { async16(gA[j], As + ao + lA[j]); gA[j] += 32; }
            #pragma unroll
            for (int j = 0; j < 4; j++) { async16(gB[j], Bs + bo + lB[j]); gB[j] += 32; }
        }
        const u16* ra = As + cur * 4096;
        const u16* rb = Bs + cur * 8192;
        bf16x8 af[4][2], bfv[2][2];
        #pragma unroll
        for (int m = 0; m < 4; m++)
            #pragma unroll
            for (int kk = 0; kk < 2; kk++)
                af[m][kk] = *(const bf16x8*)&ra[RD_A(m, kk, l)];
        #pragma unroll
        for (int n = 0; n < 2; n++)
            #pragma unroll
            for (int kk = 0; kk < 2; kk++)
                bfv[n][kk] = *(const bf16x8*)&rb[RD_B(w, n, kk, l)];
        #pragma unroll
        for (int kk = 0; kk < 2; kk++)
            #pragma unroll
            for (int m = 0; m < 4; m++)
                #pragma unroll
                for (int n = 0; n < 2; n++)
                    acc[m][n] = __builtin_amdgcn_mfma_f32_32x32x16_bf16(
                        af[m][kk], bfv[n][kk], acc[m][n], 0, 0, 0);
        __syncthreads();                          // drains vmcnt: next buf ready
        cur ^= 1;
    }

    // epilogue: C/D 32x32 mapping col=lane&31, row=(reg&3)+8*(reg>>2)+4*(lane>>5)
    #pragma unroll
    for (int m = 0; m < 4; m++)
        #pragma unroll
        for (int n = 0; n < 2; n++) {
            int col = n0 + w * 64 + n * 32 + lr;
            #pragma unroll
            for (int reg = 0; reg < 16; reg++) {
                int row = m0 + m * 32 + (reg & 3) + 8 * (reg >> 2) + 4 * h;
                C[(size_t)row * DIM + col] = f2bf(acc[m][n][reg]);
            }
        }
}

// ---------------------------------------------------------------------------
// K3: out[s][b][f] = sum_d xb[b][s][d] * CT[b][f][d] + bb[b][f]
// grid = 1024 blocks (16 Mtile x 4 Ntile x 16 batch), XCD-swizzled
// ---------------------------------------------------------------------------
__global__ __launch_bounds__(256, 2)
void gemm2_kernel(const u16* __restrict__ xb,
                  const u16* __restrict__ CT,
                  const float* __restrict__ bb,
                  float* __restrict__ out)
{
    int bid = blockIdx.x;
    int virt = ((bid & 7) << 7) + (bid >> 3);     // bijective, 1024 % 8 == 0
    int b    = virt >> 6;                         // 64 blocks per batch
    int rem  = virt & 63;
    int s0   = (rem >> 2) << 7;                   // s-tile base (128)
    int f0   = (rem & 3) << 8;                    // f-tile base (256)

    const u16* A  = xb + (size_t)b * SEQ * DIM;   // [s][d]
    const u16* Bm = CT + (size_t)b * DIM * DIM;   // [f][d]

    __shared__ u16 As[2 * 128 * 32];
    __shared__ u16 Bs[2 * 256 * 32];

    int tid = threadIdx.x;
    int w = tid >> 6, l = tid & 63;
    int lr = l & 31, h = l >> 5;

    int srow = l >> 2;
    int chunk = (l & 3) ^ (srow & 3);
    const u16* gA[2]; const u16* gB[4];
    int lA[2], lB[4];
    #pragma unroll
    for (int j = 0; j < 2; j++) {
        int row = w * 32 + j * 16 + srow;
        gA[j] = A + (size_t)(s0 + row) * DIM + chunk * 8;
        lA[j] = (w * 32 + j * 16) * 32;
    }
    #pragma unroll
    for (int j = 0; j < 4; j++) {
        int row = w * 64 + j * 16 + srow;
        gB[j] = Bm + (size_t)(f0 + row) * DIM + chunk * 8;
        lB[j] = (w * 64 + j * 16) * 32;
    }

    f32x16 acc[4][2];
    #pragma unroll
    for (int m = 0; m < 4; m++)
        #pragma unroll
        for (int n = 0; n < 2; n++)
            #pragma unroll
            for (int e = 0; e < 16; e++) acc[m][n][e] = 0.f;

    #pragma unroll
    for (int j = 0; j < 2; j++) async16(gA[j], As + lA[j]);
    #pragma unroll
    for (int j = 0; j < 4; j++) async16(gB[j], Bs + lB[j]);
    #pragma unroll
    for (int j = 0; j < 2; j++) gA[j] += 32;
    #pragma unroll
    for (int j = 0; j < 4; j++) gB[j] += 32;
    __syncthreads();

    int cur = 0;
    for (int t = 0; t < DIM / 32; t++) {
        if (t + 1 < DIM / 32) {
            int ao = (cur ^ 1) * 4096, bo = (cur ^ 1) * 8192;
            #pragma unroll
            for (int j = 0; j < 2; j++) { async16(gA[j], As + ao + lA[j]); gA[j] += 32; }
            #pragma unroll
            for (int j = 0; j < 4; j++) { async16(gB[j], Bs + bo + lB[j]); gB[j] += 32; }
        }
        const u16* ra = As + cur * 4096;
        const u16* rb = Bs + cur * 8192;
        bf16x8 af[4][2], bfv[2][2];
        #pragma unroll
        for (int m = 0; m < 4; m++)
            #pragma unroll
            for (int kk = 0; kk < 2; kk++)
                af[m][kk] = *(const bf16x8*)&ra[RD_A(m, kk, l)];
        #pragma unroll
        for (int n = 0; n < 2; n++)
            #pragma unroll
            for (int kk = 0; kk < 2; kk++)
                bfv[n][kk] = *(const bf16x8*)&rb[RD_B(w, n, kk, l)];
        #pragma unroll
        for (int kk = 0; kk < 2; kk++)
            #pragma unroll
            for (int m = 0; m < 4; m++)
                #pragma unroll
                for (int n = 0; n < 2; n++)
                    acc[m][n] = __builtin_amdgcn_mfma_f32_32x32x16_bf16(
                        af[m][kk], bfv[n][kk], acc[m][n], 0, 0, 0);
        __syncthreads();
        cur ^= 1;
    }

    #pragma unroll
    for (int n = 0; n < 2; n++) {
        int col = f0 + w * 64 + n * 32 + lr;
        float bv = bb[b * DIM + col];
        #pragma unroll
        for (int m = 0; m < 4; m++)
            #pragma unroll
            for (int reg = 0; reg < 16; reg++) {
                int row = s0 + m * 32 + (reg & 3) + 8 * (reg >> 2) + 4 * h;
                out[((size_t)row * BZ + b) * DIM + col] = acc[m][n][reg] + bv;
            }
    }
}

extern "C" void kernel_launch(void* const* d_in, const int* in_sizes, int n_in,
                              void* d_out, int out_size, void* d_ws, size_t ws_size,
                              hipStream_t stream)
{
    const float* x        = (const float*)d_in[0];
    const int*   lang_ids = (const int*)d_in[1];
    const float* W_base   = (const float*)d_in[2];
    const float* b_base   = (const float*)d_in[3];
    const float* W        = (const float*)d_in[4];
    const float* bias     = (const float*)d_in[5];
    const int*   dict_len = (const int*)d_in[6];
    float* out = (float*)d_out;

    char* ws = (char*)d_ws;
    u16*  Wt  = (u16*)ws;                                   // 2 MB
    u16*  Wbt = (u16*)(ws + (size_t)(2u << 20));            // 32 MB
    u16*  CT  = (u16*)(ws + (size_t)(34u << 20));           // 32 MB
    float* bb = (float*)(ws + (size_t)(66u << 20));         // 64 KB
    u16*  xb  = (u16*)(ws + (size_t)(67u << 20));           // 64 MB

    convert_x<<<dim3(SEQ, 1, 1), 256, 0, stream>>>(x, xb);
    transpose_cvt<<<dim3(32, 32, 17), dim3(32, 8, 1), 0, stream>>>(
        W, W_base, lang_ids, dict_len, Wt, Wbt);
    bb_kernel<<<dim3(4096, 1, 1), 256, 0, stream>>>(
        Wbt, b_base, bias, lang_ids, dict_len, bb);
    gemm1_kernel<<<dim3(512, 1, 1), 256, 0, stream>>>(Wbt, Wt, CT);
    gemm2_kernel<<<dim3(1024, 1, 1), 256, 0, stream>>>(xb, CT, bb, out);
}

// Round 4
// 430.701 us; speedup vs baseline: 1.0257x; 1.0257x over previous
//
#include <hip/hip_runtime.h>
#include <stdint.h>

typedef unsigned short u16;
typedef unsigned int u32;
typedef __bf16 bf16x8 __attribute__((ext_vector_type(8)));
typedef float f32x4 __attribute__((ext_vector_type(4)));

#define SEQ 2048
#define BZ 16
#define DIM 1024

__device__ __forceinline__ u16 f2bf(float f) {
    union { float f; u32 u; } a; a.f = f;
    u32 r = a.u + 0x7FFFu + ((a.u >> 16) & 1u);   // RNE
    return (u16)(r >> 16);
}
__device__ __forceinline__ float bf2f(u16 u) {
    union { u32 u; float f; } a; a.u = ((u32)u) << 16;
    return a.f;
}
__device__ __forceinline__ void async16(const u16* g, u16* l) {
    __builtin_amdgcn_global_load_lds(
        (const __attribute__((address_space(1))) void*)g,
        (__attribute__((address_space(3))) void*)l, 16, 0, 0);
}

// ---------------------------------------------------------------------------
// prep: fused convert_x + transpose_cvt (block-partitioned, bodies verbatim)
//   bid < SEQ:   xb[b][s][d] = bf16(x[s][b][d])
//   bid >= SEQ:  z<16: Wbt[z][f][e] = W[id_z][e][f]; z==16: Wt[d][e]=W_base[e][d]
// ---------------------------------------------------------------------------
__global__ void prep_kernel(const float* __restrict__ x,
                            const float* __restrict__ W,
                            const float* __restrict__ W_base,
                            const int* __restrict__ lang_ids,
                            const int* __restrict__ dict_len,
                            u16* __restrict__ xb,
                            u16* __restrict__ Wt,
                            u16* __restrict__ Wbt)
{
    int bid = blockIdx.x;
    int t = threadIdx.x;
    if (bid < SEQ) {
        int s = bid;
        const float4* src = (const float4*)(x + (size_t)s * BZ * DIM);
        #pragma unroll
        for (int j = 0; j < 16; j++) {
            int idx = j * 256 + t;              // float4 index in [0, 4096)
            float4 v = src[idx];
            int e = idx * 4;
            int b = e >> 10, d = e & 1023;
            u32 lo = f2bf(v.x) | ((u32)f2bf(v.y) << 16);
            u32 hi = f2bf(v.z) | ((u32)f2bf(v.w) << 16);
            *(uint2*)(xb + ((size_t)b * SEQ + s) * DIM + d) = make_uint2(lo, hi);
        }
        return;
    }
    int tid2 = bid - SEQ;
    int z = tid2 >> 10;                           // 0..16
    int yx = tid2 & 1023;
    int by = yx >> 5, bx = yx & 31;
    const float* S;
    u16* D;
    if (z < BZ) {
        int id = dict_len[0] - 1 - lang_ids[z];
        S = W + (size_t)id * DIM * DIM;
        D = Wbt + (size_t)z * DIM * DIM;
    } else {
        S = W_base;
        D = Wt;
    }
    __shared__ float tile[32][33];
    int tx = t & 31, ty = t >> 5;                 // 32 x 8
    int x0 = bx * 32, y0 = by * 32;
    #pragma unroll
    for (int i = 0; i < 4; i++)
        tile[ty + 8 * i][tx] = S[(size_t)(y0 + ty + 8 * i) * DIM + x0 + tx];
    __syncthreads();
    #pragma unroll
    for (int i = 0; i < 4; i++)
        D[(size_t)(x0 + ty + 8 * i) * DIM + y0 + tx] = f2bf(tile[tx][ty + 8 * i]);
}

// ---------------------------------------------------------------------------
// K1: bb[b][f] = sum_e b_base[e] * Wbt[b][f][e]  + bias[id_b][f]
// ---------------------------------------------------------------------------
__global__ void bb_kernel(const u16* __restrict__ Wbt,
                          const float* __restrict__ b_base,
                          const float* __restrict__ bias,
                          const int* __restrict__ lang_ids,
                          const int* __restrict__ dict_len,
                          float* __restrict__ bb)
{
    int gw = blockIdx.x * 4 + (threadIdx.x >> 6);
    int b = gw >> 10;
    int f = gw & 1023;
    int lane = threadIdx.x & 63;
    const u16* row = Wbt + ((size_t)b * DIM + f) * DIM;
    float s = 0.f;
    #pragma unroll
    for (int i = 0; i < DIM / 64; i++)
        s += bf2f(row[lane + 64 * i]) * b_base[lane + 64 * i];
    #pragma unroll
    for (int off = 32; off; off >>= 1)
        s += __shfl_xor(s, off, 64);
    if (lane == 0) {
        int id = dict_len[0] - 1 - lang_ids[b];
        bb[b * DIM + f] = s + bias[(size_t)id * DIM + f];
    }
}

// ---------------------------------------------------------------------------
// Shared GEMM geometry: block tile 128(M) x 256(N), BK=32, 4 waves (1Mx4N),
// wave tile 128x64 as 8x4 frags of mfma_f32_16x16x32_bf16.
// LDS: A [128][32] u16 + B [256][32] u16, double-buffered = 48 KiB, LINEAR
// layout (round-1's measured-good access shape: 16-row frags, quad slots).
// Per iter per wave: 12 ds_read_b128 feed 32 MFMA (42.7 FLOP/LDS-byte).
// ---------------------------------------------------------------------------

// ---------------------------------------------------------------------------
// K2: CT[b][f][d] = sum_e Wbt[b][f][e] * Wt[d][e]   (bf16 out)
// grid = 512 blocks (8 Mtile x 4 Ntile x 16 batch), XCD-swizzled
// ---------------------------------------------------------------------------
__global__ __launch_bounds__(256, 2)
void gemm1_kernel(const u16* __restrict__ Wbt,
                  const u16* __restrict__ Wt,
                  u16* __restrict__ CT)
{
    int bid = blockIdx.x;
    int virt = ((bid & 7) << 6) + (bid >> 3);     // bijective, 512 % 8 == 0
    int b    = virt >> 5;                         // 32 blocks per batch
    int rem  = virt & 31;
    int m0   = (rem >> 2) << 7;                   // f-tile base (128)
    int n0   = (rem & 3) << 8;                    // d-tile base (256)

    const u16* A = Wbt + (size_t)b * DIM * DIM;   // [f][e]
    const u16* B = Wt;                            // [d][e]
    u16* C = CT + (size_t)b * DIM * DIM;          // [f][d]

    __shared__ u16 As[2 * 128 * 32];
    __shared__ u16 Bs[2 * 256 * 32];

    int tid = threadIdx.x;
    int w = tid >> 6, l = tid & 63;
    int lr = l & 15, quad = l >> 4;

    // staging: per thread 2 A-loads + 4 B-loads of 16B (linear slots)
    int srow = l >> 2;                            // row within 16-row group
    int chunk = l & 3;
    const u16* gA[2]; const u16* gB[4];
    int lA[2], lB[4];
    #pragma unroll
    for (int j = 0; j < 2; j++) {
        int row = w * 32 + j * 16 + srow;
        gA[j] = A + (size_t)(m0 + row) * DIM + chunk * 8;
        lA[j] = (w * 32 + j * 16) * 32;           // wave-uniform LDS base
    }
    #pragma unroll
    for (int j = 0; j < 4; j++) {
        int row = w * 64 + j * 16 + srow;
        gB[j] = B + (size_t)(n0 + row) * DIM + chunk * 8;
        lB[j] = (w * 64 + j * 16) * 32;
    }

    f32x4 acc[8][4];
    #pragma unroll
    for (int m = 0; m < 8; m++)
        #pragma unroll
        for (int n = 0; n < 4; n++)
            #pragma unroll
            for (int e = 0; e < 4; e++) acc[m][n][e] = 0.f;

    // prologue: stage K-tile 0 into buffer 0
    #pragma unroll
    for (int j = 0; j < 2; j++) async16(gA[j], As + lA[j]);
    #pragma unroll
    for (int j = 0; j < 4; j++) async16(gB[j], Bs + lB[j]);
    #pragma unroll
    for (int j = 0; j < 2; j++) gA[j] += 32;
    #pragma unroll
    for (int j = 0; j < 4; j++) gB[j] += 32;
    __syncthreads();

    int cur = 0;
    for (int t = 0; t < DIM / 32; t++) {
        if (t + 1 < DIM / 32) {                   // stage next tile -> other buf
            int ao = (cur ^ 1) * 4096, bo = (cur ^ 1) * 8192;
            #pragma unroll
            for (int j = 0; j < 2; j++) { async16(gA[j], As + ao + lA[j]); gA[j] += 32; }
            #pragma unroll
            for (int j = 0; j < 4; j++) { async16(gB[j], Bs + bo + lB[j]); gB[j] += 32; }
        }
        const u16* ra = As + cur * 4096;
        const u16* rb = Bs + cur * 8192;
        bf16x8 af[8], bfv[4];
        #pragma unroll
        for (int m = 0; m < 8; m++)
            af[m] = *(const bf16x8*)&ra[(m * 16 + lr) * 32 + quad * 8];
        #pragma unroll
        for (int n = 0; n < 4; n++)
            bfv[n] = *(const bf16x8*)&rb[(w * 64 + n * 16 + lr) * 32 + quad * 8];
        #pragma unroll
        for (int m = 0; m < 8; m++)
            #pragma unroll
            for (int n = 0; n < 4; n++)
                acc[m][n] = __builtin_amdgcn_mfma_f32_16x16x32_bf16(
                    af[m], bfv[n], acc[m][n], 0, 0, 0);
        __syncthreads();                          // drains vmcnt: next buf ready
        cur ^= 1;
    }
    #pragma unroll
    for (int m = 0; m < 8; m++) {
        int fr = m0 + m * 16 + quad * 4;
        #pragma unroll
        for (int n = 0; n < 4; n++) {
            int dc = n0 + w * 64 + n * 16 + lr;
            #pragma unroll
            for (int rr = 0; rr < 4; rr++)
                C[(size_t)(fr + rr) * DIM + dc] = f2bf(acc[m][n][rr]);
        }
    }
}

// ---------------------------------------------------------------------------
// K3: out[s][b][f] = sum_d xb[b][s][d] * CT[b][f][d] + bb[b][f]
// grid = 1024 blocks (16 Mtile x 4 Ntile x 16 batch), XCD-swizzled
// ---------------------------------------------------------------------------
__global__ __launch_bounds__(256, 2)
void gemm2_kernel(const u16* __restrict__ xb,
                  const u16* __restrict__ CT,
                  const float* __restrict__ bb,
                  float* __restrict__ out)
{
    int bid = blockIdx.x;
    int virt = ((bid & 7) << 7) + (bid >> 3);     // bijective, 1024 % 8 == 0
    int b    = virt >> 6;                         // 64 blocks per batch
    int rem  = virt & 63;
    int s0   = (rem >> 2) << 7;                   // s-tile base (128), 16 tiles
    int f0   = (rem & 3) << 8;                    // f-tile base (256), 4 tiles

    const u16* A  = xb + (size_t)b * SEQ * DIM;   // [s][d]
    const u16* Bm = CT + (size_t)b * DIM * DIM;   // [f][d]

    __shared__ u16 As[2 * 128 * 32];
    __shared__ u16 Bs[2 * 256 * 32];

    int tid = threadIdx.x;
    int w = tid >> 6, l = tid & 63;
    int lr = l & 15, quad = l >> 4;

    int srow = l >> 2;
    int chunk = l & 3;
    const u16* gA[2]; const u16* gB[4];
    int lA[2], lB[4];
    #pragma unroll
    for (int j = 0; j < 2; j++) {
        int row = w * 32 + j * 16 + srow;
        gA[j] = A + (size_t)(s0 + row) * DIM + chunk * 8;
        lA[j] = (w * 32 + j * 16) * 32;
    }
    #pragma unroll
    for (int j = 0; j < 4; j++) {
        int row = w * 64 + j * 16 + srow;
        gB[j] = Bm + (size_t)(f0 + row) * DIM + chunk * 8;
        lB[j] = (w * 64 + j * 16) * 32;
    }

    f32x4 acc[8][4];
    #pragma unroll
    for (int m = 0; m < 8; m++)
        #pragma unroll
        for (int n = 0; n < 4; n++)
            #pragma unroll
            for (int e = 0; e < 4; e++) acc[m][n][e] = 0.f;

    #pragma unroll
    for (int j = 0; j < 2; j++) async16(gA[j], As + lA[j]);
    #pragma unroll
    for (int j = 0; j < 4; j++) async16(gB[j], Bs + lB[j]);
    #pragma unroll
    for (int j = 0; j < 2; j++) gA[j] += 32;
    #pragma unroll
    for (int j = 0; j < 4; j++) gB[j] += 32;
    __syncthreads();

    int cur = 0;
    for (int t = 0; t < DIM / 32; t++) {
        if (t + 1 < DIM / 32) {
            int ao = (cur ^ 1) * 4096, bo = (cur ^ 1) * 8192;
            #pragma unroll
            for (int j = 0; j < 2; j++) { async16(gA[j], As + ao + lA[j]); gA[j] += 32; }
            #pragma unroll
            for (int j = 0; j < 4; j++) { async16(gB[j], Bs + bo + lB[j]); gB[j] += 32; }
        }
        const u16* ra = As + cur * 4096;
        const u16* rb = Bs + cur * 8192;
        bf16x8 af[8], bfv[4];
        #pragma unroll
        for (int m = 0; m < 8; m++)
            af[m] = *(const bf16x8*)&ra[(m * 16 + lr) * 32 + quad * 8];
        #pragma unroll
        for (int n = 0; n < 4; n++)
            bfv[n] = *(const bf16x8*)&rb[(w * 64 + n * 16 + lr) * 32 + quad * 8];
        #pragma unroll
        for (int m = 0; m < 8; m++)
            #pragma unroll
            for (int n = 0; n < 4; n++)
                acc[m][n] = __builtin_amdgcn_mfma_f32_16x16x32_bf16(
                    af[m], bfv[n], acc[m][n], 0, 0, 0);
        __syncthreads();
        cur ^= 1;
    }

    #pragma unroll
    for (int n = 0; n < 4; n++) {
        int col = f0 + w * 64 + n * 16 + lr;
        float bv = bb[b * DIM + col];
        #pragma unroll
        for (int m = 0; m < 8; m++) {
            int sr = s0 + m * 16 + quad * 4;
            #pragma unroll
            for (int rr = 0; rr < 4; rr++)
                out[((size_t)(sr + rr) * BZ + b) * DIM + col] = acc[m][n][rr] + bv;
        }
    }
}

extern "C" void kernel_launch(void* const* d_in, const int* in_sizes, int n_in,
                              void* d_out, int out_size, void* d_ws, size_t ws_size,
                              hipStream_t stream)
{
    const float* x        = (const float*)d_in[0];
    const int*   lang_ids = (const int*)d_in[1];
    const float* W_base   = (const float*)d_in[2];
    const float* b_base   = (const float*)d_in[3];
    const float* W        = (const float*)d_in[4];
    const float* bias     = (const float*)d_in[5];
    const int*   dict_len = (const int*)d_in[6];
    float* out = (float*)d_out;

    char* ws = (char*)d_ws;
    u16*  Wt  = (u16*)ws;                                   // 2 MB
    u16*  Wbt = (u16*)(ws + (size_t)(2u << 20));            // 32 MB
    u16*  CT  = (u16*)(ws + (size_t)(34u << 20));           // 32 MB
    float* bb = (float*)(ws + (size_t)(66u << 20));         // 64 KB
    u16*  xb  = (u16*)(ws + (size_t)(67u << 20));           // 64 MB

    prep_kernel<<<dim3(SEQ + 17 * 1024, 1, 1), 256, 0, stream>>>(
        x, W, W_base, lang_ids, dict_len, xb, Wt, Wbt);
    bb_kernel<<<dim3(4096, 1, 1), 256, 0, stream>>>(
        Wbt, b_base, bias, lang_ids, dict_len, bb);
    gemm1_kernel<<<dim3(512, 1, 1), 256, 0, stream>>>(Wbt, Wt, CT);
    gemm2_kernel<<<dim3(1024, 1, 1), 256, 0, stream>>>(xb, CT, bb, out);
}

// Round 5
// 418.954 us; speedup vs baseline: 1.0544x; 1.0280x over previous
//
#include <hip/hip_runtime.h>
#include <stdint.h>

typedef unsigned short u16;
typedef unsigned int u32;
typedef __bf16 bf16x8 __attribute__((ext_vector_type(8)));
typedef float f32x4 __attribute__((ext_vector_type(4)));

#define SEQ 2048
#define BZ 16
#define DIM 1024

#define WAIT_VM6()   asm volatile("s_waitcnt vmcnt(6)" ::: "memory")
#define WAIT_VM0()   asm volatile("s_waitcnt vmcnt(0)" ::: "memory")
#define MEMFENCE()   asm volatile("" ::: "memory")

__device__ __forceinline__ u16 f2bf(float f) {
    union { float f; u32 u; } a; a.f = f;
    u32 r = a.u + 0x7FFFu + ((a.u >> 16) & 1u);   // RNE
    return (u16)(r >> 16);
}
__device__ __forceinline__ float bf2f(u16 u) {
    union { u32 u; float f; } a; a.u = ((u32)u) << 16;
    return a.f;
}
__device__ __forceinline__ void async16(const u16* g, u16* l) {
    __builtin_amdgcn_global_load_lds(
        (const __attribute__((address_space(1))) void*)g,
        (__attribute__((address_space(3))) void*)l, 16, 0, 0);
}
// first batch index with the same language id (ids are a bijection of lang_ids)
__device__ __forceinline__ int rep_of(const int* __restrict__ lang_ids, int b) {
    int my = lang_ids[b];
    #pragma unroll
    for (int j = 0; j < BZ; j++)
        if (lang_ids[j] == my) return j;
    return b;
}

// ---------------------------------------------------------------------------
// prep: fused convert_x + transpose_cvt (block-partitioned)
//   bid < SEQ:   xb[b][s][d] = bf16(x[s][b][d])
//   bid >= SEQ:  z<16: Wbt[z][f][e] = W[id_z][e][f] (skipped for dup langs);
//                z==16: Wt[d][e]=W_base[e][d]
// ---------------------------------------------------------------------------
__global__ void prep_kernel(const float* __restrict__ x,
                            const float* __restrict__ W,
                            const float* __restrict__ W_base,
                            const int* __restrict__ lang_ids,
                            const int* __restrict__ dict_len,
                            u16* __restrict__ xb,
                            u16* __restrict__ Wt,
                            u16* __restrict__ Wbt)
{
    int bid = blockIdx.x;
    int t = threadIdx.x;
    if (bid < SEQ) {
        int s = bid;
        const float4* src = (const float4*)(x + (size_t)s * BZ * DIM);
        #pragma unroll
        for (int j = 0; j < 16; j++) {
            int idx = j * 256 + t;              // float4 index in [0, 4096)
            float4 v = src[idx];
            int e = idx * 4;
            int b = e >> 10, d = e & 1023;
            u32 lo = f2bf(v.x) | ((u32)f2bf(v.y) << 16);
            u32 hi = f2bf(v.z) | ((u32)f2bf(v.w) << 16);
            *(uint2*)(xb + ((size_t)b * SEQ + s) * DIM + d) = make_uint2(lo, hi);
        }
        return;
    }
    int tid2 = bid - SEQ;
    int z = tid2 >> 10;                           // 0..16
    int yx = tid2 & 1023;
    int by = yx >> 5, bx = yx & 31;
    const float* S;
    u16* D;
    if (z < BZ) {
        if (rep_of(lang_ids, z) != z) return;     // duplicate language: skip
        int id = dict_len[0] - 1 - lang_ids[z];
        S = W + (size_t)id * DIM * DIM;
        D = Wbt + (size_t)z * DIM * DIM;
    } else {
        S = W_base;
        D = Wt;
    }
    __shared__ float tile[32][33];
    int tx = t & 31, ty = t >> 5;                 // 32 x 8
    int x0 = bx * 32, y0 = by * 32;
    #pragma unroll
    for (int i = 0; i < 4; i++)
        tile[ty + 8 * i][tx] = S[(size_t)(y0 + ty + 8 * i) * DIM + x0 + tx];
    __syncthreads();
    #pragma unroll
    for (int i = 0; i < 4; i++)
        D[(size_t)(x0 + ty + 8 * i) * DIM + y0 + tx] = f2bf(tile[tx][ty + 8 * i]);
}

// ---------------------------------------------------------------------------
// K1: bb[b][f] = sum_e b_base[e] * Wbt[b][f][e]  + bias[id_b][f]
//     (only for representative batches; consumers index bb[rep[b]])
// ---------------------------------------------------------------------------
__global__ void bb_kernel(const u16* __restrict__ Wbt,
                          const float* __restrict__ b_base,
                          const float* __restrict__ bias,
                          const int* __restrict__ lang_ids,
                          const int* __restrict__ dict_len,
                          float* __restrict__ bb)
{
    int gw = blockIdx.x * 4 + (threadIdx.x >> 6);
    int b = gw >> 10;
    if (rep_of(lang_ids, b) != b) return;         // duplicate language: skip
    int f = gw & 1023;
    int lane = threadIdx.x & 63;
    const u16* row = Wbt + ((size_t)b * DIM + f) * DIM;
    float s = 0.f;
    #pragma unroll
    for (int i = 0; i < DIM / 64; i++)
        s += bf2f(row[lane + 64 * i]) * b_base[lane + 64 * i];
    #pragma unroll
    for (int off = 32; off; off >>= 1)
        s += __shfl_xor(s, off, 64);
    if (lane == 0) {
        int id = dict_len[0] - 1 - lang_ids[b];
        bb[b * DIM + f] = s + bias[(size_t)id * DIM + f];
    }
}

// ---------------------------------------------------------------------------
// Shared GEMM geometry (round-4 proven micro-pattern): block 128(M)x256(N),
// BK=32, 4 waves (1Mx4N), wave tile 128x64 as 8x4 frags of 16x16x32 bf16,
// LINEAR LDS [rows][32] u16, double-buffered = 48 KiB.
// NEW: counted-vmcnt pipeline — raw s_barrier + s_waitcnt vmcnt(6); next
// tile's 6 global_load_lds stay in flight across barriers (no vmcnt(0)
// drain in the main loop). 2 barriers/iter, flanked by compiler fences.
// ---------------------------------------------------------------------------

// ---------------------------------------------------------------------------
// K2: CT[b][f][d] = sum_e Wbt[b][f][e] * Wt[d][e]   (bf16 out)
// grid = 512 blocks (8 Mtile x 4 Ntile x 16 batch), XCD-swizzled
// ---------------------------------------------------------------------------
__global__ __launch_bounds__(256, 2)
void gemm1_kernel(const u16* __restrict__ Wbt,
                  const u16* __restrict__ Wt,
                  const int* __restrict__ lang_ids,
                  u16* __restrict__ CT)
{
    int bid = blockIdx.x;
    int virt = ((bid & 7) << 6) + (bid >> 3);     // bijective, 512 % 8 == 0
    int b    = virt >> 5;                         // 32 blocks per batch
    if (rep_of(lang_ids, b) != b) return;         // duplicate language: skip
    int rem  = virt & 31;
    int m0   = (rem >> 2) << 7;                   // f-tile base (128)
    int n0   = (rem & 3) << 8;                    // d-tile base (256)

    const u16* A = Wbt + (size_t)b * DIM * DIM;   // [f][e]
    const u16* B = Wt;                            // [d][e]
    u16* C = CT + (size_t)b * DIM * DIM;          // [f][d]

    __shared__ u16 As[2 * 128 * 32];
    __shared__ u16 Bs[2 * 256 * 32];

    int tid = threadIdx.x;
    int w = tid >> 6, l = tid & 63;
    int lr = l & 15, quad = l >> 4;

    int srow = l >> 2;                            // row within 16-row group
    int chunk = l & 3;
    const u16* gA[2]; const u16* gB[4];
    int lA[2], lB[4];
    #pragma unroll
    for (int j = 0; j < 2; j++) {
        int row = w * 32 + j * 16 + srow;
        gA[j] = A + (size_t)(m0 + row) * DIM + chunk * 8;
        lA[j] = (w * 32 + j * 16) * 32;           // wave-uniform LDS base
    }
    #pragma unroll
    for (int j = 0; j < 4; j++) {
        int row = w * 64 + j * 16 + srow;
        gB[j] = B + (size_t)(n0 + row) * DIM + chunk * 8;
        lB[j] = (w * 64 + j * 16) * 32;
    }

    f32x4 acc[8][4];
    #pragma unroll
    for (int m = 0; m < 8; m++)
        #pragma unroll
        for (int n = 0; n < 4; n++)
            #pragma unroll
            for (int e = 0; e < 4; e++) acc[m][n][e] = 0.f;

    // prologue: stage K-tile 0 into buffer 0
    #pragma unroll
    for (int j = 0; j < 2; j++) { async16(gA[j], As + lA[j]); gA[j] += 32; }
    #pragma unroll
    for (int j = 0; j < 4; j++) { async16(gB[j], Bs + lB[j]); gB[j] += 32; }

    int cur = 0;
    for (int t = 0; t < DIM / 32 - 1; t++) {
        // stage tile t+1 into the other buffer (stays in flight across barriers)
        int ao = (cur ^ 1) * 4096, bo = (cur ^ 1) * 8192;
        #pragma unroll
        for (int j = 0; j < 2; j++) { async16(gA[j], As + ao + lA[j]); gA[j] += 32; }
        #pragma unroll
        for (int j = 0; j < 4; j++) { async16(gB[j], Bs + bo + lB[j]); gB[j] += 32; }
        WAIT_VM6();                               // tile-t loads (oldest 6) landed
        MEMFENCE(); __builtin_amdgcn_s_barrier(); MEMFENCE();
        __builtin_amdgcn_sched_barrier(0);

        const u16* ra = As + cur * 4096;
        const u16* rb = Bs + cur * 8192;
        bf16x8 af[8], bfv[4];
        #pragma unroll
        for (int m = 0; m < 8; m++)
            af[m] = *(const bf16x8*)&ra[(m * 16 + lr) * 32 + quad * 8];
        #pragma unroll
        for (int n = 0; n < 4; n++)
            bfv[n] = *(const bf16x8*)&rb[(w * 64 + n * 16 + lr) * 32 + quad * 8];
        __builtin_amdgcn_s_setprio(1);
        #pragma unroll
        for (int m = 0; m < 8; m++)
            #pragma unroll
            for (int n = 0; n < 4; n++)
                acc[m][n] = __builtin_amdgcn_mfma_f32_16x16x32_bf16(
                    af[m], bfv[n], acc[m][n], 0, 0, 0);
        __builtin_amdgcn_s_setprio(0);
        __builtin_amdgcn_sched_barrier(0);
        MEMFENCE(); __builtin_amdgcn_s_barrier(); MEMFENCE();
        cur ^= 1;
    }
    // epilogue iteration: last tile, no further staging
    {
        WAIT_VM0();
        MEMFENCE(); __builtin_amdgcn_s_barrier(); MEMFENCE();
        __builtin_amdgcn_sched_barrier(0);
        const u16* ra = As + cur * 4096;
        const u16* rb = Bs + cur * 8192;
        bf16x8 af[8], bfv[4];
        #pragma unroll
        for (int m = 0; m < 8; m++)
            af[m] = *(const bf16x8*)&ra[(m * 16 + lr) * 32 + quad * 8];
        #pragma unroll
        for (int n = 0; n < 4; n++)
            bfv[n] = *(const bf16x8*)&rb[(w * 64 + n * 16 + lr) * 32 + quad * 8];
        #pragma unroll
        for (int m = 0; m < 8; m++)
            #pragma unroll
            for (int n = 0; n < 4; n++)
                acc[m][n] = __builtin_amdgcn_mfma_f32_16x16x32_bf16(
                    af[m], bfv[n], acc[m][n], 0, 0, 0);
    }
    #pragma unroll
    for (int m = 0; m < 8; m++) {
        int fr = m0 + m * 16 + quad * 4;
        #pragma unroll
        for (int n = 0; n < 4; n++) {
            int dc = n0 + w * 64 + n * 16 + lr;
            #pragma unroll
            for (int rr = 0; rr < 4; rr++)
                C[(size_t)(fr + rr) * DIM + dc] = f2bf(acc[m][n][rr]);
        }
    }
}

// ---------------------------------------------------------------------------
// K3: out[s][b][f] = sum_d xb[b][s][d] * CT[rep_b][f][d] + bb[rep_b][f]
// grid = 1024 blocks (16 Mtile x 4 Ntile x 16 batch), XCD-swizzled
// ---------------------------------------------------------------------------
__global__ __launch_bounds__(256, 2)
void gemm2_kernel(const u16* __restrict__ xb,
                  const u16* __restrict__ CT,
                  const float* __restrict__ bb,
                  const int* __restrict__ lang_ids,
                  float* __restrict__ out)
{
    int bid = blockIdx.x;
    int virt = ((bid & 7) << 7) + (bid >> 3);     // bijective, 1024 % 8 == 0
    int b    = virt >> 6;                         // 64 blocks per batch
    int rb_  = rep_of(lang_ids, b);               // language representative
    int rem  = virt & 63;
    int s0   = (rem >> 2) << 7;                   // s-tile base (128), 16 tiles
    int f0   = (rem & 3) << 8;                    // f-tile base (256), 4 tiles

    const u16* A  = xb + (size_t)b * SEQ * DIM;   // [s][d]
    const u16* Bm = CT + (size_t)rb_ * DIM * DIM; // [f][d]

    __shared__ u16 As[2 * 128 * 32];
    __shared__ u16 Bs[2 * 256 * 32];

    int tid = threadIdx.x;
    int w = tid >> 6, l = tid & 63;
    int lr = l & 15, quad = l >> 4;

    int srow = l >> 2;
    int chunk = l & 3;
    const u16* gA[2]; const u16* gB[4];
    int lA[2], lB[4];
    #pragma unroll
    for (int j = 0; j < 2; j++) {
        int row = w * 32 + j * 16 + srow;
        gA[j] = A + (size_t)(s0 + row) * DIM + chunk * 8;
        lA[j] = (w * 32 + j * 16) * 32;
    }
    #pragma unroll
    for (int j = 0; j < 4; j++) {
        int row = w * 64 + j * 16 + srow;
        gB[j] = Bm + (size_t)(f0 + row) * DIM + chunk * 8;
        lB[j] = (w * 64 + j * 16) * 32;
    }

    f32x4 acc[8][4];
    #pragma unroll
    for (int m = 0; m < 8; m++)
        #pragma unroll
        for (int n = 0; n < 4; n++)
            #pragma unroll
            for (int e = 0; e < 4; e++) acc[m][n][e] = 0.f;

    // prologue: stage K-tile 0 into buffer 0
    #pragma unroll
    for (int j = 0; j < 2; j++) { async16(gA[j], As + lA[j]); gA[j] += 32; }
    #pragma unroll
    for (int j = 0; j < 4; j++) { async16(gB[j], Bs + lB[j]); gB[j] += 32; }

    int cur = 0;
    for (int t = 0; t < DIM / 32 - 1; t++) {
        int ao = (cur ^ 1) * 4096, bo = (cur ^ 1) * 8192;
        #pragma unroll
        for (int j = 0; j < 2; j++) { async16(gA[j], As + ao + lA[j]); gA[j] += 32; }
        #pragma unroll
        for (int j = 0; j < 4; j++) { async16(gB[j], Bs + bo + lB[j]); gB[j] += 32; }
        WAIT_VM6();
        MEMFENCE(); __builtin_amdgcn_s_barrier(); MEMFENCE();
        __builtin_amdgcn_sched_barrier(0);

        const u16* ra = As + cur * 4096;
        const u16* rb = Bs + cur * 8192;
        bf16x8 af[8], bfv[4];
        #pragma unroll
        for (int m = 0; m < 8; m++)
            af[m] = *(const bf16x8*)&ra[(m * 16 + lr) * 32 + quad * 8];
        #pragma unroll
        for (int n = 0; n < 4; n++)
            bfv[n] = *(const bf16x8*)&rb[(w * 64 + n * 16 + lr) * 32 + quad * 8];
        __builtin_amdgcn_s_setprio(1);
        #pragma unroll
        for (int m = 0; m < 8; m++)
            #pragma unroll
            for (int n = 0; n < 4; n++)
                acc[m][n] = __builtin_amdgcn_mfma_f32_16x16x32_bf16(
                    af[m], bfv[n], acc[m][n], 0, 0, 0);
        __builtin_amdgcn_s_setprio(0);
        __builtin_amdgcn_sched_barrier(0);
        MEMFENCE(); __builtin_amdgcn_s_barrier(); MEMFENCE();
        cur ^= 1;
    }
    {
        WAIT_VM0();
        MEMFENCE(); __builtin_amdgcn_s_barrier(); MEMFENCE();
        __builtin_amdgcn_sched_barrier(0);
        const u16* ra = As + cur * 4096;
        const u16* rb = Bs + cur * 8192;
        bf16x8 af[8], bfv[4];
        #pragma unroll
        for (int m = 0; m < 8; m++)
            af[m] = *(const bf16x8*)&ra[(m * 16 + lr) * 32 + quad * 8];
        #pragma unroll
        for (int n = 0; n < 4; n++)
            bfv[n] = *(const bf16x8*)&rb[(w * 64 + n * 16 + lr) * 32 + quad * 8];
        #pragma unroll
        for (int m = 0; m < 8; m++)
            #pragma unroll
            for (int n = 0; n < 4; n++)
                acc[m][n] = __builtin_amdgcn_mfma_f32_16x16x32_bf16(
                    af[m], bfv[n], acc[m][n], 0, 0, 0);
    }

    #pragma unroll
    for (int n = 0; n < 4; n++) {
        int col = f0 + w * 64 + n * 16 + lr;
        float bv = bb[rb_ * DIM + col];
        #pragma unroll
        for (int m = 0; m < 8; m++) {
            int sr = s0 + m * 16 + quad * 4;
            #pragma unroll
            for (int rr = 0; rr < 4; rr++)
                out[((size_t)(sr + rr) * BZ + b) * DIM + col] = acc[m][n][rr] + bv;
        }
    }
}

extern "C" void kernel_launch(void* const* d_in, const int* in_sizes, int n_in,
                              void* d_out, int out_size, void* d_ws, size_t ws_size,
                              hipStream_t stream)
{
    const float* x        = (const float*)d_in[0];
    const int*   lang_ids = (const int*)d_in[1];
    const float* W_base   = (const float*)d_in[2];
    const float* b_base   = (const float*)d_in[3];
    const float* W        = (const float*)d_in[4];
    const float* bias     = (const float*)d_in[5];
    const int*   dict_len = (const int*)d_in[6];
    float* out = (float*)d_out;

    char* ws = (char*)d_ws;
    u16*  Wt  = (u16*)ws;                                   // 2 MB
    u16*  Wbt = (u16*)(ws + (size_t)(2u << 20));            // 32 MB
    u16*  CT  = (u16*)(ws + (size_t)(34u << 20));           // 32 MB
    float* bb = (float*)(ws + (size_t)(66u << 20));         // 64 KB
    u16*  xb  = (u16*)(ws + (size_t)(67u << 20));           // 64 MB

    prep_kernel<<<dim3(SEQ + 17 * 1024, 1, 1), 256, 0, stream>>>(
        x, W, W_base, lang_ids, dict_len, xb, Wt, Wbt);
    bb_kernel<<<dim3(4096, 1, 1), 256, 0, stream>>>(
        Wbt, b_base, bias, lang_ids, dict_len, bb);
    gemm1_kernel<<<dim3(512, 1, 1), 256, 0, stream>>>(Wbt, Wt, lang_ids, CT);
    gemm2_kernel<<<dim3(1024, 1, 1), 256, 0, stream>>>(xb, CT, bb, lang_ids, out);
}